// Round 1
// 84.860 us; speedup vs baseline: 1.0728x; 1.0728x over previous
//
#include <hip/hip_runtime.h>
#include <math.h>
#include <stdint.h>

#define LOG2E 1.44269504088896340736f
#define TPS 8      // j-tiles per super-step
#define JS  4      // j-range splits (313x4 blocks -> ~4.9 waves/SIMD)
#define NBUF 3     // triple-buffered LDS staging (27.6 KB -> 5 blocks/CU cap)
#define CUT -16.0f // skip exp when ALL entries have log2(K) < -16
                   // (K < 1.5e-5; dropped mass ~5e-5; measured absmax 0.0039 -> 3.5x margin)

// ROUND-8 LESSON (do not re-add): a per-wave __threadfence() finisher forced
// device-scope L2 writebacks across XCDs -> B-stream refetched from HBM
// (FETCH 6->21 MB), main kernel 3x slower. Separate finisher pass is cheaper.
//
// THIS ROUND: (1) counted-vmcnt + raw s_barrier (T4) with NBUF=3 -- the old
// __syncthreads drained vmcnt(0) every super-step, stalling all waves on the
// freshly-issued DMA; now loads stay in flight across barriers (drain-0 only
// on the last step). (2) s_j folded into beta'_j = beta_j*2^s_j and
// cut_j = CUT - s_j -> MFMA C-init is the resident a_i regs (8 v_add/tile gone,
// and the ds_read_b64 -> MFMA dependency is gone; b64 now only feeds the skip
// compare). (3) atomics -> per-split partial slabs in ws + fused sum+softplus
// finisher; prep no longer zero-inits out (40000 -> 16384 threads).

typedef _Float16 f16x8 __attribute__((ext_vector_type(8)));
typedef float f32x4 __attribute__((ext_vector_type(4)));

__device__ __forceinline__ float softplus_f(float t) {
    return (t > 20.0f) ? t : log1pf(expf(t));
}

// global -> LDS direct DMA, 16 B/lane. lds base must be wave-uniform; HW adds lane*16.
#define GLDS16(g, l)                                                     \
    __builtin_amdgcn_global_load_lds(                                    \
        (const __attribute__((address_space(1))) uint32_t*)(const void*)(g), \
        (__attribute__((address_space(3))) uint32_t*)(void*)(l), 16, 0, 0)

// ---------------- pass 1: fragment-linear f16 B workspace + folded coeffs ----------------
// Tile jt, fragment pos l = q*16+m holds c[j=jt*16+m][k=q*8..q*8+7] as f16 ->
// wave B-load = base + lane*16 B (dense, DMA-compatible).
// sbG[j] = { beta_j * 2^s_j, CUT - s_j } with s_j = -0.5*log2e*|c_j|^2.
// Pad cols: beta'=0 and cut=+3e38 (branch never taken, contribution exactly 0).
__global__ void prep_c_kernel(const float* __restrict__ c,
                              const float* __restrict__ beta,
                              _Float16* __restrict__ chiF,
                              float2* __restrict__ sbG,
                              int M, int Mp) {
    int tid = blockIdx.x * blockDim.x + threadIdx.x;
    int j = tid >> 2, q = tid & 3;
    if (j >= Mp) return;
    int jt = j >> 4, m = j & 15;
    size_t fo = (size_t)jt * 512 + (size_t)(q * 16 + m) * 8;   // halves

    float ssq = 0.0f;
    _Float16 hi[8];
    if (j < M) {
        const float4* cp = (const float4*)(c + (size_t)j * 32 + q * 8);
        float4 a = cp[0], b = cp[1];
        float vv[8] = {a.x, a.y, a.z, a.w, b.x, b.y, b.z, b.w};
#pragma unroll
        for (int t = 0; t < 8; ++t) {
            float f = vv[t];
            ssq = fmaf(f, f, ssq);
            hi[t] = (_Float16)f;
        }
    } else {
#pragma unroll
        for (int t = 0; t < 8; ++t) hi[t] = (_Float16)0.0f;
    }
    ssq += __shfl_xor(ssq, 1, 4);       // |c_j|^2 over the 4 q-threads
    ssq += __shfl_xor(ssq, 2, 4);

    *(f16x8*)(chiF + fo) = *(const f16x8*)hi;
    if (q == 0) {
        if (j < M) {
            float s = -0.5f * LOG2E * ssq;
            sbG[j] = make_float2(beta[j] * exp2f(s), CUT - s);
        } else {
            sbG[j] = make_float2(0.0f, 3.0e38f);
        }
    }
}

// ---------------- main: LDS-staged MFMA RBF matvec, counted-vmcnt pipeline ----------------
// Block = 4 waves; wave w owns TWO i-tiles (rows g*32..g*32+31, g = bx*4+w), so
// each staged B fragment feeds 2 MFMAs. blockIdx.y picks a quarter of the j-tiles.
// C layout (m89): col = lane&15, row = (lane>>4)*4 + reg.
// Pipeline: stage(s+2) issued right after the barrier; per-wave wait is
// vmcnt(#loads of stage(s+1)) = 2 (wave0: 3, carries sb) -> stage(s) proven
// complete (vmcnt retires in order), stage(s+1)/(s+2) stay in flight.
__global__ __launch_bounds__(256) void krr_mfma_lds_kernel(
    const float* __restrict__ x,
    const _Float16* __restrict__ chiF,
    const float2* __restrict__ sbG,
    float* __restrict__ part,     // JS x N partial sums
    int N, int steps)             // super-steps per j-split
{
    __shared__ f16x8 chiS[NBUF][TPS][64];                // 24 KB
    __shared__ __align__(16) float2 sbS[NBUF][TPS * 16]; // 3 KB

    const int wave = threadIdx.x >> 6;
    const int lane = threadIdx.x & 63;
    const int m    = lane & 15;
    const int quad = lane >> 4;

    const int g  = blockIdx.x * 4 + wave;    // 32-row group
    const int s0 = blockIdx.y * steps;       // this block's super-step range

    // ---- two A fragments (rows g*32+m and g*32+16+m), pre-scaled by log2e ----
    // ainit[r] = a_i for C row quad*4+r; passed directly as MFMA C-in each tile.
    f16x8 ahi1, ahi2;
    f32x4 ainit1, ainit2;
    {
        int rows[2] = {g * 32 + m, g * 32 + 16 + m};
        f16x8* ah[2] = {&ahi1, &ahi2};
        f32x4* ai[2] = {&ainit1, &ainit2};
#pragma unroll
        for (int f = 0; f < 2; ++f) {
            int rc = (rows[f] < N) ? rows[f] : (N - 1);  // clamp load; stores are guarded
            const float4* xp = (const float4*)(x + (size_t)rc * 32 + quad * 8);
            float4 v0 = xp[0], v1 = xp[1];
            float p = v0.x * v0.x + v0.y * v0.y + v0.z * v0.z + v0.w * v0.w
                    + v1.x * v1.x + v1.y * v1.y + v1.z * v1.z + v1.w * v1.w;
            p += __shfl_xor(p, 16, 64);
            p += __shfl_xor(p, 32, 64);               // |x_row|^2 over all quads
            float ai_m = -0.5f * LOG2E * p;
            float vv[8] = {v0.x, v0.y, v0.z, v0.w, v1.x, v1.y, v1.z, v1.w};
#pragma unroll
            for (int t = 0; t < 8; ++t)
                (*ah[f])[t] = (_Float16)(vv[t] * LOG2E);
#pragma unroll
            for (int r = 0; r < 4; ++r)
                (*ai[f])[r] = __shfl(ai_m, quad * 4 + r, 16);
        }
    }

    // ---- staging: 8 chi chunks (2/wave) + 1 sb chunk (wave0) per step ----
    auto stage = [&](int s, int b) {
        const _Float16* base = chiF + (size_t)(s0 + s) * TPS * 512;
#pragma unroll
        for (int ch = wave; ch < TPS; ch += 4)
            GLDS16(base + (size_t)ch * 512 + (size_t)lane * 8, &chiS[b][ch][0]);
        if (wave == 0)
            GLDS16((const char*)(sbG + (size_t)(s0 + s) * (TPS * 16)) + (size_t)lane * 16,
                   &sbS[b][0]);
    };

    stage(0, 0);
    if (steps > 1) stage(1, 1);
    float out1[4] = {0.0f, 0.0f, 0.0f, 0.0f};
    float out2[4] = {0.0f, 0.0f, 0.0f, 0.0f};

    int cb = 0;                              // compute buffer = s % NBUF
    for (int s = 0; s < steps; ++s) {
        // wait: stage(s) complete (leave stage(s+1) in flight), then barrier.
        // Single asm keeps the "memory" clobber tight around s_barrier so no
        // LDS access is moved across it. Last step has nothing in flight behind
        // it -> full drain.
        if (s + 1 < steps) {
            if (wave == 0) asm volatile("s_waitcnt vmcnt(3)\n\ts_barrier" ::: "memory");
            else           asm volatile("s_waitcnt vmcnt(2)\n\ts_barrier" ::: "memory");
        } else {
            asm volatile("s_waitcnt vmcnt(0)\n\ts_barrier" ::: "memory");
        }
        if (s + 2 < steps) {
            int nb = cb + 2; if (nb >= NBUF) nb -= NBUF;
            stage(s + 2, nb);                // writes buf all waves finished reading
        }

#pragma unroll
        for (int t = 0; t < TPS; ++t) {
            f16x8 bhi = chiS[cb][t][lane];            // ds_read_b128, lane-linear
            float2 s2 = sbS[cb][t * 16 + m];          // {beta'_j, cut_j}, broadcast
            // MFMA issues straight off the b128 read; C-in = resident a_i regs.
            f32x4 acc1 = __builtin_amdgcn_mfma_f32_16x16x32_f16(ahi1, bhi, ainit1, 0, 0, 0);
            f32x4 acc2 = __builtin_amdgcn_mfma_f32_16x16x32_f16(ahi2, bhi, ainit2, 0, 0, 0);

            // chained fmax -> v_max3 + v_max; per-lane exact threshold cut_j.
            float mx1 = fmaxf(fmaxf(fmaxf(acc1[0], acc1[1]), acc1[2]), acc1[3]);
            float mx2 = fmaxf(fmaxf(fmaxf(acc2[0], acc2[1]), acc2[2]), acc2[3]);
            if (__any(mx1 > s2.y)) {                  // wave-uniform: s_cbranch skip
#pragma unroll
                for (int r = 0; r < 4; ++r)
                    out1[r] = fmaf(s2.x, __builtin_amdgcn_exp2f(acc1[r]), out1[r]);
            }
            if (__any(mx2 > s2.y)) {
#pragma unroll
                for (int r = 0; r < 4; ++r)
                    out2[r] = fmaf(s2.x, __builtin_amdgcn_exp2f(acc2[r]), out2[r]);
            }
        }
        cb = (cb + 1 == NBUF) ? 0 : cb + 1;
    }

    // ---- reduce over 16 cols (lane bits 0..3), plain store to this split's slab ----
    float* oas[2] = {out1, out2};
#pragma unroll
    for (int f = 0; f < 2; ++f) {
        const int rowbase = g * 32 + f * 16;
#pragma unroll
        for (int r = 0; r < 4; ++r) {
            float v = oas[f][r];
            v += __shfl_xor(v, 1, 64);
            v += __shfl_xor(v, 2, 64);
            v += __shfl_xor(v, 4, 64);
            v += __shfl_xor(v, 8, 64);
            if (m == r) {
                int row = rowbase + quad * 4 + r;
                if (row < N) part[(size_t)blockIdx.y * N + row] = v;
            }
        }
    }
}

// ---------------- pass 3: sum JS partial slabs + softplus (deterministic) ----------------
__global__ void finish_kernel(const float* __restrict__ part,
                              float* __restrict__ out, int N) {
    int i4 = (blockIdx.x * blockDim.x + threadIdx.x) * 4;
    if (i4 + 3 < N) {
        float4 s = *(const float4*)(part + i4);
#pragma unroll
        for (int k = 1; k < JS; ++k) {
            float4 p = *(const float4*)(part + (size_t)k * N + i4);
            s.x += p.x; s.y += p.y; s.z += p.z; s.w += p.w;
        }
        *(float4*)(out + i4) = make_float4(softplus_f(s.x), softplus_f(s.y),
                                           softplus_f(s.z), softplus_f(s.w));
    } else if (i4 < N) {
        for (int u = i4; u < N && u < i4 + 4; ++u) {
            float s = 0.0f;
            for (int k = 0; k < JS; ++k) s += part[(size_t)k * N + u];
            out[u] = softplus_f(s);
        }
    }
}

// ---------------- fallback path (ws too small): round-1 VALU kernel ----------------
#define CHUNK_MAX 512
__global__ void zero_out_kernel(float* __restrict__ out, int n) {
    int i = blockIdx.x * blockDim.x + threadIdx.x;
    if (i < n) out[i] = 0.0f;
}
__global__ void softplus_kernel(float* __restrict__ out, int n) {
    int i = blockIdx.x * blockDim.x + threadIdx.x;
    if (i < n) out[i] = softplus_f(out[i]);
}
__global__ __launch_bounds__(64, 4) void krr_partial_kernel(
    const float* __restrict__ x, const float* __restrict__ c,
    const float* __restrict__ beta, float* __restrict__ out,
    int N, int M, int chunk)
{
    __shared__ float2 sw[CHUNK_MAX];
    const int lane = threadIdx.x;
    const int j0 = blockIdx.y * chunk;
    const int j1 = min(M, j0 + chunk);
    for (int j = j0 + lane; j < j1; j += 64) {
        const float4* cr = (const float4*)(c + (size_t)j * 32);
        float s = 0.0f;
#pragma unroll
        for (int q = 0; q < 8; ++q) {
            float4 v = cr[q];
            s = fmaf(v.x, v.x, s); s = fmaf(v.y, v.y, s);
            s = fmaf(v.z, v.z, s); s = fmaf(v.w, v.w, s);
        }
        sw[j - j0] = make_float2(-0.5f * LOG2E * s, beta[j]);
    }
    __syncthreads();
    const int i = blockIdx.x * 64 + lane;
    const bool valid = (i < N);
    const float4* xrow = (const float4*)(x + (size_t)(valid ? i : 0) * 32);
    float xr[32]; float xsq = 0.0f;
#pragma unroll
    for (int q = 0; q < 8; ++q) {
        float4 v = xrow[q];
        xsq = fmaf(v.x, v.x, xsq); xsq = fmaf(v.y, v.y, xsq);
        xsq = fmaf(v.z, v.z, xsq); xsq = fmaf(v.w, v.w, xsq);
        xr[4*q+0] = v.x * LOG2E; xr[4*q+1] = v.y * LOG2E;
        xr[4*q+2] = v.z * LOG2E; xr[4*q+3] = v.w * LOG2E;
    }
    const float ai = -0.5f * LOG2E * xsq;
    float acc = 0.0f;
#pragma unroll 2
    for (int j = j0; j < j1; ++j) {
        const float4* cr = (const float4*)(c + (size_t)j * 32);
        const float2 s2 = sw[j - j0];
        float d = ai + s2.x;
#pragma unroll
        for (int q = 0; q < 8; ++q) {
            float4 v = cr[q];
            d = fmaf(xr[4*q+0], v.x, d); d = fmaf(xr[4*q+1], v.y, d);
            d = fmaf(xr[4*q+2], v.z, d); d = fmaf(xr[4*q+3], v.w, d);
        }
        acc = fmaf(s2.y, __builtin_amdgcn_exp2f(d), acc);
    }
    if (valid) atomicAdd(out + i, acc);
}

extern "C" void kernel_launch(void* const* d_in, const int* in_sizes, int n_in,
                              void* d_out, int out_size, void* d_ws, size_t ws_size,
                              hipStream_t stream) {
    const float* x    = (const float*)d_in[0];   // (N, 32)
    const float* c    = (const float*)d_in[1];   // (M, 32)
    const float* beta = (const float*)d_in[2];   // (M,)
    float* out = (float*)d_out;                  // (N,)

    const int N = out_size;                      // 40000
    const int M = in_sizes[2];                   // 4000
    const int JT = (M + 15) / 16;                // 250 j-tiles
    const int SPAN = TPS * JS;                   // tile granularity: 32
    const int JTS = ((JT + SPAN - 1) / SPAN) * SPAN;  // padded: 256
    const int steps = JTS / SPAN;                // super-steps per j-split: 8
    const int Mp = JTS * 16;                     // 4096 padded cols

    // ws: chiF (JTS*512 halves) | sbG (Mp float2) | part (JS*N floats) ~ 0.93 MB
    const size_t chi_bytes = (size_t)JTS * 1024;
    const size_t sb_bytes  = (size_t)Mp * 8;
    const size_t need = chi_bytes + sb_bytes + (size_t)JS * N * 4;

    if (ws_size >= need) {
        _Float16* chiF = (_Float16*)d_ws;
        float2*   sbG  = (float2*)((char*)d_ws + chi_bytes);
        float*    part = (float*)((char*)d_ws + chi_bytes + sb_bytes);

        prep_c_kernel<<<dim3((Mp * 4 + 255) / 256), dim3(256), 0, stream>>>(
            c, beta, chiF, sbG, M, Mp);

        const int groups = (N + 31) / 32;            // 1250 32-row groups
        const int bx = (groups + 3) / 4;             // 313 blocks x 4 waves
        krr_mfma_lds_kernel<<<dim3(bx, JS), dim3(256), 0, stream>>>(
            x, chiF, sbG, part, N, steps);

        const int fthreads = (N + 3) / 4;
        finish_kernel<<<dim3((fthreads + 255) / 256), dim3(256), 0, stream>>>(
            part, out, N);
    } else {
        zero_out_kernel<<<dim3((N + 255) / 256), dim3(256), 0, stream>>>(out, N);
        int jc = (M + CHUNK_MAX - 1) / CHUNK_MAX;
        if (jc < 8) jc = 8;
        int chunk = (M + jc - 1) / jc;
        dim3 grid((N + 63) / 64, jc);
        krr_partial_kernel<<<grid, dim3(64), 0, stream>>>(x, c, beta, out, N, M, chunk);
        softplus_kernel<<<dim3((N + 255) / 256), dim3(256), 0, stream>>>(out, N);
    }
}